// Round 11
// baseline (715.473 us; speedup 1.0000x reference)
//
#include <hip/hip_runtime.h>

// ---------- types ----------
typedef __attribute__((ext_vector_type(8))) short short8;   // 8 bf16 (4 VGPRs)
typedef __attribute__((ext_vector_type(4))) float f32x4;    // MFMA accumulator

__device__ __forceinline__ unsigned short f2bf(float f) {
  union { float f; unsigned u; } x{f};
  unsigned r = x.u + 0x7FFFu + ((x.u >> 16) & 1u);  // round-to-nearest-even
  return (unsigned short)(r >> 16);
}

// async global->LDS, 16B per lane; LDS dest is wave-uniform base + lane*16
__device__ __forceinline__ void gload_lds16(const void* g, void* l) {
  __builtin_amdgcn_global_load_lds(
      (__attribute__((address_space(1))) void*)((unsigned long long)g),
      (__attribute__((address_space(3))) void*)(unsigned)((unsigned long long)l),
      16, 0, 0);
}

// 6-stage H64 butterfly over the first index of tile[64][64]
__device__ __forceinline__ void butterfly64(float (*tile)[64], int t) {
  const int c  = t & 63;
  const int pb = t >> 6;
#pragma unroll
  for (int h = 1; h < 64; h <<= 1) {
#pragma unroll
    for (int k = 0; k < 8; ++k) {
      const int p  = pb + (k << 2);
      const int j1 = ((p & ~(h - 1)) << 1) | (p & (h - 1));
      const int j2 = j1 + h;
      const float a = tile[j1][c], b = tile[j2][c];
      tile[j1][c] = a + b;
      tile[j2][c] = a - b;
    }
    __syncthreads();
  }
}

// ---------- K1: fused trellis decode + col-FWHT(low 6 bits of o) -> W[4096][4096] ----------
__global__ void k_deq_col1(const int* __restrict__ trellis,
                           const float* __restrict__ tlut,
                           float* __restrict__ W) {
  __shared__ unsigned short words[16][32];   // 16 tiles * 32 words
  __shared__ float tile[64][64];
  const int t  = threadIdx.x;
  const int rg = blockIdx.x >> 6;            // o-group (64 rows)
  const int cg = blockIdx.x & 63;            // i-group (64 cols)
#pragma unroll
  for (int r = 0; r < 2; ++r) {
    const int ff = t + (r << 8);
    const int a = ff >> 7, rw = ff & 127;
    const int src = ((rg * 4 + a) * 256 + cg * 4) * 32 + rw;
    ((unsigned short*)words)[a * 128 + rw] = (unsigned short)(trellis[src] & 0xFFFF);
  }
  __syncthreads();
#pragma unroll
  for (int r = 0; r < 8; ++r) {
    const int f  = t + (r << 8);
    const int tl = f >> 7, s = f & 127;
    const unsigned short* w = words[tl];
    unsigned state = 0;
#pragma unroll
    for (int j = 0; j < 4; ++j) {
      const int ss = (s - j) & 127;
      state |= (((unsigned)w[ss >> 2] >> (12 - 4 * (ss & 3))) & 0xFu) << (4 * j);
    }
    const float2 v = *(const float2*)(tlut + (size_t)state * 2);
    const int o = ((tl >> 2) << 4) + (s >> 3);
    const int i = ((tl & 3) << 4) + ((s & 7) << 1);
    tile[o][i]     = v.x;
    tile[o][i + 1] = v.y;
  }
  __syncthreads();
  butterfly64(tile, t);
  const size_t base = ((size_t)(rg * 64)) * 4096 + cg * 64;
#pragma unroll
  for (int k = 0; k < 4; ++k) {
    const int idx = t + (k << 8);
    const int r = idx >> 4, c4 = idx & 15;
    *(float4*)(W + base + (size_t)r * 4096 + (c4 << 2)) = *(float4*)(&tile[r][c4 << 2]);
  }
}

// ---------- K2: FWHT over rows (i axis, full H4096), in place, * 1/64 ----------
__global__ void k_fwht_row(float* __restrict__ W) {
  __shared__ float row[4096];
  const int t = threadIdx.x;
  float* g = W + ((size_t)blockIdx.x << 12);
#pragma unroll
  for (int k = 0; k < 4; ++k) {
    const int e = (t + (k << 8)) << 2;
    *(float4*)(row + e) = *(const float4*)(g + e);
  }
  __syncthreads();
  for (int h = 1; h < 4096; h <<= 1) {
#pragma unroll
    for (int k = 0; k < 8; ++k) {
      const int p  = t + (k << 8);
      const int j1 = ((p & ~(h - 1)) << 1) | (p & (h - 1));
      const int j2 = j1 + h;
      const float a = row[j1], b = row[j2];
      row[j1] = a + b;
      row[j2] = a - b;
    }
    __syncthreads();
  }
#pragma unroll
  for (int k = 0; k < 4; ++k) {
    const int e = (t + (k << 8)) << 2;
    float4 v = *(float4*)(row + e);
    v.x *= 0.015625f; v.y *= 0.015625f; v.z *= 0.015625f; v.w *= 0.015625f;
    *(float4*)(g + e) = v;
  }
}

// ---------- K3: col FWHT, high 6 bits of o, *1/64, *SV[o]*SU[i], -> bf16 Mt[N][K] ----------
__global__ void k_fwht_col2(const float* __restrict__ W,
                            const float* __restrict__ SU,
                            const float* __restrict__ SV,
                            unsigned short* __restrict__ Mt) {
  __shared__ float tile[64][64];
  const int t  = threadIdx.x;
  const int b  = blockIdx.x >> 6;   // row residue (low bits)
  const int cg = blockIdx.x & 63;
#pragma unroll
  for (int k = 0; k < 4; ++k) {
    const int idx = t + (k << 8);
    const int a = idx >> 4, c4 = idx & 15;
    const int row = (a << 6) + b;
    *(float4*)(&tile[a][c4 << 2]) =
        *(const float4*)(W + (size_t)row * 4096 + ((size_t)cg << 6) + (c4 << 2));
  }
  __syncthreads();
  butterfly64(tile, t);
#pragma unroll
  for (int k = 0; k < 4; ++k) {
    const int idx = t + (k << 8);
    const int a = idx >> 4, c4 = idx & 15;
    const int row = (a << 6) + b;                 // o (OUT index)
    const int col0 = (cg << 6) + (c4 << 2);       // i (IN index)
    const float sv = SV[row] * 0.015625f;
    const float4 su = *(const float4*)(SU + col0);
    const float4 v = *(float4*)(&tile[a][c4 << 2]);
    ushort4 o;
    o.x = f2bf(v.x * sv * su.x);
    o.y = f2bf(v.y * sv * su.y);
    o.z = f2bf(v.z * sv * su.z);
    o.w = f2bf(v.w * sv * su.w);
    *(ushort4*)(Mt + (size_t)row * 4096 + col0) = o;
  }
}

// ---------- K4: x fp32 -> bf16 ----------
__global__ void k_cvt_x(const float* __restrict__ x, unsigned short* __restrict__ xb) {
  const long long n4 = (long long)16384 * 4096 / 4;
  long long i = (long long)blockIdx.x * blockDim.x + threadIdx.x;
  const long long stride = (long long)gridDim.x * blockDim.x;
  for (; i < n4; i += stride) {
    const float4 v = *(const float4*)(x + i * 4);
    ushort4 o;
    o.x = f2bf(v.x); o.y = f2bf(v.y); o.z = f2bf(v.z); o.w = f2bf(v.w);
    *(ushort4*)(xb + i * 4) = o;
  }
}

// ---------- K5: 256x256 GEMM, 4 waves x 128x128 tile (1 wave/SIMD), ILP pipeline ----------
// The 474us plateau is additive LDS+MFMA time under 2-wave/SIMD lockstep:
// per BK=32 tile/CU, matrix pipes 1242 cyc + LDS ~960 cyc ~ measured 2100 (sum,
// not max). Fix: 4 waves, one per SIMD, each owning 128x128 output:
//  - LDS bytes/FLOP halves (1/128+1/128): 16 ds_read_b128/wave/tile.
//  - acc[8][8]=256 VGPR fits at 1 wave/SIMD (512 budget; R7 spilled at 2/SIMD).
//  - TWO named operand sets (rule #20): tile j+1's 16 reads issue during tile
//    j's 64-MFMA cluster (1242 cyc) -> LDS fully hidden by ILP, not TLP.
// Quad-buffer BK=32 (128 KiB), vmcnt(8) per tile (2-tile prefetch lead, m135
// oldest-first), ONE barrier/tile. Swizzle: R10-verified conflict-free pair
// (source chunk c^((row>>1)&3), read chunk q^((lr>>1)&3)).
#define BARRIER __builtin_amdgcn_s_barrier()

#define STAGE(buf, jj) do { \
  const unsigned short* aJ = aRow + ((jj) << 5); \
  const unsigned short* bJ = bRow + ((jj) << 5); \
  gload_lds16(aJ,                  smem +         (buf)*16384 +         w1k); \
  gload_lds16(aJ + ( 64ull << 12), smem +         (buf)*16384 +  4096 + w1k); \
  gload_lds16(aJ + (128ull << 12), smem +         (buf)*16384 +  8192 + w1k); \
  gload_lds16(aJ + (192ull << 12), smem +         (buf)*16384 + 12288 + w1k); \
  gload_lds16(bJ,                  smem + 65536 + (buf)*16384 +         w1k); \
  gload_lds16(bJ + ( 64ull << 12), smem + 65536 + (buf)*16384 +  4096 + w1k); \
  gload_lds16(bJ + (128ull << 12), smem + 65536 + (buf)*16384 +  8192 + w1k); \
  gload_lds16(bJ + (192ull << 12), smem + 65536 + (buf)*16384 + 12288 + w1k); \
} while (0)

#define READS(afX, bbX, buf) do { _Pragma("unroll") \
  for (int ni = 0; ni < 8; ++ni) \
    bbX[ni] = *(const short8*)(smem + 65536 + (buf)*16384 + wcB + ni*1024 + cx); \
  _Pragma("unroll") \
  for (int mi = 0; mi < 8; ++mi) \
    afX[mi] = *(const short8*)(smem + (buf)*16384 + wrA + mi*1024 + cx); \
} while (0)

#define MMAS(afX, bbX) do { _Pragma("unroll") \
  for (int mi = 0; mi < 8; ++mi) { _Pragma("unroll") \
    for (int ni = 0; ni < 8; ++ni) \
      acc[mi][ni] = __builtin_amdgcn_mfma_f32_16x16x32_bf16(afX[mi], bbX[ni], acc[mi][ni], 0, 0, 0); \
  } } while (0)

#define WAITV(N) asm volatile("s_waitcnt vmcnt(" #N ")" ::: "memory")

__global__ void __launch_bounds__(256, 1)
k_gemm8(const unsigned short* __restrict__ A,
        const unsigned short* __restrict__ B,
        float* __restrict__ C) {
  extern __shared__ char smem[];
  const int t    = threadIdx.x;
  const int lane = t & 63, w = t >> 6;          // 4 waves, 1 per SIMD
  const int wr   = w >> 1, wc = w & 1;          // 2 x 2 wave grid, 128x128 each
  const int lr   = lane & 15, q = lane >> 4;
  const int w1k  = w * 1024;
  const int wrA  = wr * 8192, wcB = wc * 8192;

  const int nt = blockIdx.x & 15;               // 16 N-tiles (nt fastest: A-panel reuse)
  const int mt = blockIdx.x >> 4;               // 64 M-tiles

  // frag read offset within a [128 rows][64B] region (R10-verified conflict-free)
  const int cx = lr * 64 + ((q ^ ((lr >> 1) & 3)) << 4);

  // staging source: row = 64*i + (t>>2), chunk pre-swizzled c^((row>>1)&3)
  const int srow  = t >> 2;
  const int csrc8 = (((t & 3) ^ ((t >> 3) & 3)) << 3);
  const unsigned short* aRow = A + (((size_t)(mt * 256 + srow)) << 12) + csrc8;
  const unsigned short* bRow = B + (((size_t)(nt * 256 + srow)) << 12) + csrc8;

  short8 afA[8], bbA[8], afB[8], bbB[8];
  f32x4  acc[8][8];
#pragma unroll
  for (int i = 0; i < 8; ++i)
#pragma unroll
    for (int j = 0; j < 8; ++j) acc[i][j] = (f32x4){0.f, 0.f, 0.f, 0.f};

  // prologue: stage tiles 0,1,2 (24 loads); drain tile 0; preload its operands
  STAGE(0, 0); STAGE(1, 1); STAGE(2, 2);
  WAITV(16); BARRIER;
  READS(afA, bbA, 0);

  // 128 K-tiles of 32; tile j lives in buf j&3
  for (int g = 0; g < 62; ++g) {
    const int j = 2 * g;
    WAITV(8); BARRIER;                  // tile j+1 landed (all waves)
    STAGE((j + 3) & 3, j + 3);
    READS(afB, bbB, (j + 1) & 3);       // operands for tile j+1 (fills under MMAS)
    MMAS(afA, bbA);                     // tile j
    WAITV(8); BARRIER;                  // tile j+2 landed
    STAGE((j + 4) & 3, j + 4);
    READS(afA, bbA, (j + 2) & 3);
    MMAS(afB, bbB);                     // tile j+1
  }
  // tail: tiles 124..127 (124..126 staged; 127 staged here)
  WAITV(8); BARRIER;
  STAGE(3, 127);
  READS(afB, bbB, 1);                   // tile 125
  MMAS(afA, bbA);                       // tile 124 (buf 0)
  WAITV(8); BARRIER;
  READS(afA, bbA, 2);                   // tile 126
  MMAS(afB, bbB);                       // tile 125
  WAITV(0); BARRIER;
  READS(afB, bbB, 3);                   // tile 127
  MMAS(afA, bbA);                       // tile 126
  MMAS(afB, bbB);                       // tile 127

  // epilogue: C/D layout col=lane&15, row=(lane>>4)*4+reg
  float* cbase = C + (((size_t)(mt * 256 + wr * 128 + q * 4)) << 12)
               + nt * 256 + wc * 128 + lr;
#pragma unroll
  for (int mi = 0; mi < 8; ++mi)
#pragma unroll
    for (int ni = 0; ni < 8; ++ni)
#pragma unroll
      for (int r = 0; r < 4; ++r)
        cbase[(((size_t)(mi * 16 + r)) << 12) + ni * 16] = acc[mi][ni][r];
}

extern "C" void kernel_launch(void* const* d_in, const int* in_sizes, int n_in,
                              void* d_out, int out_size, void* d_ws, size_t ws_size,
                              hipStream_t stream) {
  const float* x       = (const float*)d_in[0];   // (8,2048,4096) fp32
  const int*   trellis = (const int*)d_in[1];     // (65536,32) int32
  const float* tlut    = (const float*)d_in[2];   // (65536,2) fp32
  const float* SU      = (const float*)d_in[3];   // (4096,)
  const float* SV      = (const float*)d_in[4];   // (4096,)
  float* out = (float*)d_out;

  char* ws = (char*)d_ws;
  float*          W  = (float*)ws;                            // 64 MiB fp32
  unsigned short* Mt = (unsigned short*)(ws + (64ull << 20)); // 32 MiB bf16 [N][K]
  unsigned short* xb = (unsigned short*)(ws + (96ull << 20)); // 128 MiB bf16 [M][K]

  hipFuncSetAttribute(reinterpret_cast<const void*>(&k_gemm8),
                      hipFuncAttributeMaxDynamicSharedMemorySize, 131072);

  hipLaunchKernelGGL(k_deq_col1,  dim3(4096),  dim3(256), 0, stream, trellis, tlut, W);
  hipLaunchKernelGGL(k_fwht_row,  dim3(4096),  dim3(256), 0, stream, W);
  hipLaunchKernelGGL(k_fwht_col2, dim3(4096),  dim3(256), 0, stream, W, SU, SV, Mt);
  hipLaunchKernelGGL(k_cvt_x,     dim3(2048),  dim3(256), 0, stream, x, xb);
  hipLaunchKernelGGL(k_gemm8,     dim3(1024),  dim3(256), 131072, stream, xb, Mt, out);
}

// Round 12
// 628.889 us; speedup vs baseline: 1.1377x; 1.1377x over previous
//
#include <hip/hip_runtime.h>

// ---------- types ----------
typedef __attribute__((ext_vector_type(8))) short short8;   // 8 bf16 (4 VGPRs)
typedef __attribute__((ext_vector_type(4))) float f32x4;    // MFMA accumulator

__device__ __forceinline__ unsigned short f2bf(float f) {
  union { float f; unsigned u; } x{f};
  unsigned r = x.u + 0x7FFFu + ((x.u >> 16) & 1u);  // round-to-nearest-even
  return (unsigned short)(r >> 16);
}

// async global->LDS, 16B per lane; LDS dest = wave-uniform base + lane*16
__device__ __forceinline__ void gload_lds16(const void* g, void* l) {
  __builtin_amdgcn_global_load_lds(
      (__attribute__((address_space(1))) void*)((unsigned long long)g),
      (__attribute__((address_space(3))) void*)(unsigned)((unsigned long long)l),
      16, 0, 0);
}

// 6-stage H64 butterfly over the first index of tile[64][64]
__device__ __forceinline__ void butterfly64(float (*tile)[64], int t) {
  const int c  = t & 63;
  const int pb = t >> 6;
#pragma unroll
  for (int h = 1; h < 64; h <<= 1) {
#pragma unroll
    for (int k = 0; k < 8; ++k) {
      const int p  = pb + (k << 2);
      const int j1 = ((p & ~(h - 1)) << 1) | (p & (h - 1));
      const int j2 = j1 + h;
      const float a = tile[j1][c], b = tile[j2][c];
      tile[j1][c] = a + b;
      tile[j2][c] = a - b;
    }
    __syncthreads();
  }
}

// ---------- K1: fused trellis decode + col-FWHT(low 6 bits of o) -> W[4096][4096] ----------
__global__ void k_deq_col1(const int* __restrict__ trellis,
                           const float* __restrict__ tlut,
                           float* __restrict__ W) {
  __shared__ unsigned short words[16][32];   // 16 tiles * 32 words
  __shared__ float tile[64][64];
  const int t  = threadIdx.x;
  const int rg = blockIdx.x >> 6;            // o-group (64 rows)
  const int cg = blockIdx.x & 63;            // i-group (64 cols)
#pragma unroll
  for (int r = 0; r < 2; ++r) {
    const int ff = t + (r << 8);
    const int a = ff >> 7, rw = ff & 127;
    const int src = ((rg * 4 + a) * 256 + cg * 4) * 32 + rw;
    ((unsigned short*)words)[a * 128 + rw] = (unsigned short)(trellis[src] & 0xFFFF);
  }
  __syncthreads();
#pragma unroll
  for (int r = 0; r < 8; ++r) {
    const int f  = t + (r << 8);
    const int tl = f >> 7, s = f & 127;
    const unsigned short* w = words[tl];
    unsigned state = 0;
#pragma unroll
    for (int j = 0; j < 4; ++j) {
      const int ss = (s - j) & 127;
      state |= (((unsigned)w[ss >> 2] >> (12 - 4 * (ss & 3))) & 0xFu) << (4 * j);
    }
    const float2 v = *(const float2*)(tlut + (size_t)state * 2);
    const int o = ((tl >> 2) << 4) + (s >> 3);
    const int i = ((tl & 3) << 4) + ((s & 7) << 1);
    tile[o][i]     = v.x;
    tile[o][i + 1] = v.y;
  }
  __syncthreads();
  butterfly64(tile, t);
  const size_t base = ((size_t)(rg * 64)) * 4096 + cg * 64;
#pragma unroll
  for (int k = 0; k < 4; ++k) {
    const int idx = t + (k << 8);
    const int r = idx >> 4, c4 = idx & 15;
    *(float4*)(W + base + (size_t)r * 4096 + (c4 << 2)) = *(float4*)(&tile[r][c4 << 2]);
  }
}

// ---------- K2: FWHT over rows (i axis, full H4096), in place, * 1/64 ----------
__global__ void k_fwht_row(float* __restrict__ W) {
  __shared__ float row[4096];
  const int t = threadIdx.x;
  float* g = W + ((size_t)blockIdx.x << 12);
#pragma unroll
  for (int k = 0; k < 4; ++k) {
    const int e = (t + (k << 8)) << 2;
    *(float4*)(row + e) = *(const float4*)(g + e);
  }
  __syncthreads();
  for (int h = 1; h < 4096; h <<= 1) {
#pragma unroll
    for (int k = 0; k < 8; ++k) {
      const int p  = t + (k << 8);
      const int j1 = ((p & ~(h - 1)) << 1) | (p & (h - 1));
      const int j2 = j1 + h;
      const float a = row[j1], b = row[j2];
      row[j1] = a + b;
      row[j2] = a - b;
    }
    __syncthreads();
  }
#pragma unroll
  for (int k = 0; k < 4; ++k) {
    const int e = (t + (k << 8)) << 2;
    float4 v = *(float4*)(row + e);
    v.x *= 0.015625f; v.y *= 0.015625f; v.z *= 0.015625f; v.w *= 0.015625f;
    *(float4*)(g + e) = v;
  }
}

// ---------- K3: col FWHT, high 6 bits of o, *1/64, *SV[o]*SU[i], -> bf16 Mt[N][K] ----------
__global__ void k_fwht_col2(const float* __restrict__ W,
                            const float* __restrict__ SU,
                            const float* __restrict__ SV,
                            unsigned short* __restrict__ Mt) {
  __shared__ float tile[64][64];
  const int t  = threadIdx.x;
  const int b  = blockIdx.x >> 6;   // row residue (low bits)
  const int cg = blockIdx.x & 63;
#pragma unroll
  for (int k = 0; k < 4; ++k) {
    const int idx = t + (k << 8);
    const int a = idx >> 4, c4 = idx & 15;
    const int row = (a << 6) + b;
    *(float4*)(&tile[a][c4 << 2]) =
        *(const float4*)(W + (size_t)row * 4096 + ((size_t)cg << 6) + (c4 << 2));
  }
  __syncthreads();
  butterfly64(tile, t);
#pragma unroll
  for (int k = 0; k < 4; ++k) {
    const int idx = t + (k << 8);
    const int a = idx >> 4, c4 = idx & 15;
    const int row = (a << 6) + b;                 // o (OUT index)
    const int col0 = (cg << 6) + (c4 << 2);       // i (IN index)
    const float sv = SV[row] * 0.015625f;
    const float4 su = *(const float4*)(SU + col0);
    const float4 v = *(float4*)(&tile[a][c4 << 2]);
    ushort4 o;
    o.x = f2bf(v.x * sv * su.x);
    o.y = f2bf(v.y * sv * su.y);
    o.z = f2bf(v.z * sv * su.z);
    o.w = f2bf(v.w * sv * su.w);
    *(ushort4*)(Mt + (size_t)row * 4096 + col0) = o;
  }
}

// ---------- K4: x fp32 -> bf16 ----------
__global__ void k_cvt_x(const float* __restrict__ x, unsigned short* __restrict__ xb) {
  const long long n4 = (long long)16384 * 4096 / 4;
  long long i = (long long)blockIdx.x * blockDim.x + threadIdx.x;
  const long long stride = (long long)gridDim.x * blockDim.x;
  for (; i < n4; i += stride) {
    const float4 v = *(const float4*)(x + i * 4);
    ushort4 o;
    o.x = f2bf(v.x); o.y = f2bf(v.y); o.z = f2bf(v.z); o.w = f2bf(v.w);
    *(ushort4*)(xb + i * 4) = o;
  }
}

// ---------- K5: 256x256 GEMM, BK=32 quad-buffer, uniform 8/4 phases ----------
// Fixes vs prior attempts:
//  * R10's deep-prefetch test was INVALID (2x redundant A staging insts, LDS
//    overflow into neighbor buf, over-draining vmcnt(8) gate). Correct here:
//    4 insts/tile (2A+2B, rows 0-127/128-255), exact 3-tile data lead,
//    vmcnt(8) = the 2 younger tiles' 8 insts stay in flight.
//  * R3/R4's read distribution was 12/8/4/0 per phase; m201's uniform 8/4
//    keeps the LDS port evenly fed (m196: interleave pattern worth +-27%).
//    Per tile: P1 reads af[0..3]+bb[0..3] (8) -> 16 MFMA (rows 0-3 quadrant);
//    P2 reads af[4..7] (4) -> 16 MFMA (rows 4-7). bb stays live across P1/P2.
//  * ONE barrier/tile. WAR-safe: stage target buf (j+3)&3 was last READ in
//    tile j-1; every wave's tile j-1 ds_reads retired (lgkm before its MFMAs)
//    before it reaches the tile-j barrier; stages issue after that barrier.
//  * 2 waves/SIMD (R11 showed 1 wave/SIMD serializes VALU with MFMA).
//  * Swizzle: R10-measured conflict-free BK=32 pair (store c^((row>>1)&3) via
//    pre-swizzled global source, read chunk q^((lr>>1)&3)).
#define BARRIER __builtin_amdgcn_s_barrier()
#define WAITV(N) asm volatile("s_waitcnt vmcnt(" #N ")" ::: "memory")

#define STAGE_A2(buf, jj) do { \
  const unsigned short* aJ = aRow + ((jj) << 5); \
  gload_lds16(aJ,                  smem + (buf)*16384 +        w1k); \
  gload_lds16(aJ + (128ull << 12), smem + (buf)*16384 + 8192 + w1k); \
} while (0)
#define STAGE_B2(buf, jj) do { \
  const unsigned short* bJ = bRow + ((jj) << 5); \
  gload_lds16(bJ,                  smem + 65536 + (buf)*16384 +        w1k); \
  gload_lds16(bJ + (128ull << 12), smem + 65536 + (buf)*16384 + 8192 + w1k); \
} while (0)

#define READ_P1(buf) do { _Pragma("unroll") \
  for (int ni = 0; ni < 4; ++ni) \
    bb[ni] = *(const short8*)(smem + 65536 + (buf)*16384 + wc4k + ni*1024 + cx); \
  _Pragma("unroll") \
  for (int mi = 0; mi < 4; ++mi) \
    af[mi] = *(const short8*)(smem + (buf)*16384 + wr8k + mi*1024 + cx); \
} while (0)
#define READ_P2(buf) do { _Pragma("unroll") \
  for (int mi = 0; mi < 4; ++mi) \
    ag[mi] = *(const short8*)(smem + (buf)*16384 + wr8k + (4+mi)*1024 + cx); \
} while (0)

#define MMAQ(afX, mb) do { _Pragma("unroll") \
  for (int mi = 0; mi < 4; ++mi) { _Pragma("unroll") \
    for (int ni = 0; ni < 4; ++ni) \
      acc[(mb)+mi][ni] = __builtin_amdgcn_mfma_f32_16x16x32_bf16(afX[mi], bb[ni], acc[(mb)+mi][ni], 0, 0, 0); \
  } } while (0)

// one K-tile of 32: gate, barrier, {stageA | P1 reads | 16 MFMA}, {stageB | P2 reads | 16 MFMA}
#define KT(buf, SA, SB, N) do { \
  WAITV(N); BARRIER; \
  SA; READ_P1(buf); \
  __builtin_amdgcn_s_setprio(1); MMAQ(af, 0); __builtin_amdgcn_s_setprio(0); \
  SB; READ_P2(buf); \
  __builtin_amdgcn_s_setprio(1); MMAQ(ag, 4); __builtin_amdgcn_s_setprio(0); \
} while (0)

__global__ void __launch_bounds__(512, 2)
k_gemm8(const unsigned short* __restrict__ A,
        const unsigned short* __restrict__ B,
        float* __restrict__ C) {
  extern __shared__ char smem[];
  const int t    = threadIdx.x;
  const int lane = t & 63, w = t >> 6;
  const int wr   = w >> 2, wc = w & 3;          // 2 x 4 wave grid, 128x64 out each
  const int lr   = lane & 15, q = lane >> 4;
  const int w1k  = w * 1024;
  const int wr8k = wr * 8192, wc4k = wc * 4096;

  const int nt = blockIdx.x & 15;               // 16 N-tiles (nt fastest: A-panel reuse)
  const int mt = blockIdx.x >> 4;               // 64 M-tiles

  // frag read offset in a [256 rows][64B] buf: row*64 + ((q^((lr>>1)&3))<<4)
  const int cx = lr * 64 + ((q ^ ((lr >> 1) & 3)) << 4);

  // staging source: row = t>>2 (+128 for inst2), chunk pre-swizzled c^((row>>1)&3)
  const int srow  = t >> 2;
  const int csrc8 = (((t & 3) ^ ((t >> 3) & 3)) << 3);
  const unsigned short* aRow = A + (((size_t)(mt * 256 + srow)) << 12) + csrc8;
  const unsigned short* bRow = B + (((size_t)(nt * 256 + srow)) << 12) + csrc8;

  short8 af[4], ag[4], bb[4];
  f32x4  acc[8][4];
#pragma unroll
  for (int i = 0; i < 8; ++i)
#pragma unroll
    for (int j = 0; j < 4; ++j) acc[i][j] = (f32x4){0.f, 0.f, 0.f, 0.f};

  // prologue: stage tiles 0,1,2 into bufs 0,1,2 (12 insts in flight)
  STAGE_A2(0, 0); STAGE_B2(0, 0);
  STAGE_A2(1, 1); STAGE_B2(1, 1);
  STAGE_A2(2, 2); STAGE_B2(2, 2);

  // 128 K-tiles of 32; tile j uses buf j&3, stages tile j+3 into buf (j+3)&3
  for (int g = 0; g < 31; ++g) {
    const int j = 4 * g;
    KT(0, STAGE_A2(3, j + 3), STAGE_B2(3, j + 3), 8);
    KT(1, STAGE_A2(0, j + 4), STAGE_B2(0, j + 4), 8);
    KT(2, STAGE_A2(1, j + 5), STAGE_B2(1, j + 5), 8);
    KT(3, STAGE_A2(2, j + 6), STAGE_B2(2, j + 6), 8);
  }
  // tail: tiles 124..127 (124 stages tile 127; then drain 8->4->0)
  KT(0, STAGE_A2(3, 127), STAGE_B2(3, 127), 8);
  KT(1, , , 8);
  KT(2, , , 4);
  KT(3, , , 0);

  // epilogue: C/D layout col=lane&15, row=(lane>>4)*4+reg
  float* cbase = C + (((size_t)(mt * 256 + wr * 128 + q * 4)) << 12)
               + nt * 256 + wc * 64 + lr;
#pragma unroll
  for (int mi = 0; mi < 8; ++mi)
#pragma unroll
    for (int ni = 0; ni < 4; ++ni)
#pragma unroll
      for (int r = 0; r < 4; ++r)
        cbase[(((size_t)(mi * 16 + r)) << 12) + ni * 16] = acc[mi][ni][r];
}

extern "C" void kernel_launch(void* const* d_in, const int* in_sizes, int n_in,
                              void* d_out, int out_size, void* d_ws, size_t ws_size,
                              hipStream_t stream) {
  const float* x       = (const float*)d_in[0];   // (8,2048,4096) fp32
  const int*   trellis = (const int*)d_in[1];     // (65536,32) int32
  const float* tlut    = (const float*)d_in[2];   // (65536,2) fp32
  const float* SU      = (const float*)d_in[3];   // (4096,)
  const float* SV      = (const float*)d_in[4];   // (4096,)
  float* out = (float*)d_out;

  char* ws = (char*)d_ws;
  float*          W  = (float*)ws;                            // 64 MiB fp32
  unsigned short* Mt = (unsigned short*)(ws + (64ull << 20)); // 32 MiB bf16 [N][K]
  unsigned short* xb = (unsigned short*)(ws + (96ull << 20)); // 128 MiB bf16 [M][K]

  hipFuncSetAttribute(reinterpret_cast<const void*>(&k_gemm8),
                      hipFuncAttributeMaxDynamicSharedMemorySize, 131072);

  hipLaunchKernelGGL(k_deq_col1,  dim3(4096),  dim3(256), 0, stream, trellis, tlut, W);
  hipLaunchKernelGGL(k_fwht_row,  dim3(4096),  dim3(256), 0, stream, W);
  hipLaunchKernelGGL(k_fwht_col2, dim3(4096),  dim3(256), 0, stream, W, SU, SV, Mt);
  hipLaunchKernelGGL(k_cvt_x,     dim3(4096),  dim3(256), 0, stream, x, xb);
  hipLaunchKernelGGL(k_gemm8,     dim3(1024),  dim3(512), 131072, stream, xb, Mt, out);
}